// Round 1
// baseline (404.628 us; speedup 1.0000x reference)
//
#include <hip/hip_runtime.h>
#include <float.h>

// Shapes (fixed by the problem)
#define Bsz 2
#define Ssz 4096
#define Hsz 12
#define Gsz 64
#define Wsz 513            // W_LOC
#define Csz (Gsz + Wsz)    // 577 channels
#define ROW (Hsz * Csz)    // 6924 floats per (b,s) row
#define HALF 256           // (Wsz-1)/2

// Workspace layout (floats)
#define COLSUM_OFF  0
#define COLSUM_SZ   ((size_t)Bsz * Ssz * Wsz)          // 4,202,496
#define PSUM_OFF    COLSUM_SZ
#define PSUM_SZ     ((size_t)Bsz * Ssz)                // 8192
#define GACC_OFF    (PSUM_OFF + PSUM_SZ)
#define GACC_SZ     ((size_t)Bsz * Gsz)                // 128

// K1: per-row h-sum. 8 rows per block, 256 threads.
__global__ __launch_bounds__(256) void k1_rowsum(
    const float* __restrict__ probs, const float* __restrict__ mask,
    float* __restrict__ colsum, float* __restrict__ gacc)
{
    __shared__ float lds[ROW];   // 27,696 B
    const int t = threadIdx.x;
    const int row0 = blockIdx.x * 8;
    const int b = row0 / Ssz;    // 8 | 4096, so all 8 rows share b
    float g = 0.f;               // thread t<64 accumulates global channel t

    for (int r = 0; r < 8; ++r) {
        const int row = row0 + r;
        // stage row with float4 loads (row byte offset = row*27696, 16B aligned)
        const float4* src = (const float4*)(probs + (size_t)row * ROW);
        float4* dst = (float4*)lds;
        for (int idx = t; idx < ROW / 4; idx += 256) dst[idx] = src[idx];
        __syncthreads();

        const float scale = (mask[row] < 0.f) ? 0.f : 1.f;
        const int s = row - b * Ssz;
        for (int c = t; c < Csz; c += 256) {
            float v = 0.f;
            #pragma unroll
            for (int h = 0; h < Hsz; ++h) v += lds[h * Csz + c];
            v *= scale;
            if (c < Gsz) g += v;
            else colsum[((size_t)b * Ssz + s) * Wsz + (c - Gsz)] = v;
        }
        __syncthreads();
    }
    if (t < Gsz) atomicAdd(&gacc[b * Gsz + t], g);
}

// K2: anti-diagonal sums -> psum. grid (3 s-chunks, S/256 i-chunks, B)
__global__ __launch_bounds__(256) void k2_diag(
    const float* __restrict__ colsum, float* __restrict__ psum)
{
    const int t  = threadIdx.x;
    const int i0 = blockIdx.y * 256;
    const int b  = blockIdx.z;
    const int i  = i0 + t;
    // s-chunk covers [i0-256+256*chunk, +256)
    int s_begin = i0 - 256 + (int)blockIdx.x * 256;
    int s_end   = s_begin + 256;
    if (s_begin < 0) s_begin = 0;
    if (s_end > Ssz) s_end = Ssz;

    // addr of colsum[b][s][i+256-s] = b*S*W + s*(W-1) + (i+256)
    const float* base = colsum + (size_t)b * Ssz * Wsz + (i + HALF);
    float acc = 0.f;
    for (int s = s_begin; s < s_end; ++s) {
        int j = i + HALF - s;
        if (j >= 0 && j < Wsz) acc += base[(size_t)s * (Wsz - 1)];
    }
    atomicAdd(&psum[b * Ssz + i], acc);
}

// K3: honor the index arrays: psum[loc_b,loc_i] += gacc[glob_b,glob_i]
__global__ void k3_scatter(const int* __restrict__ loc_b, const int* __restrict__ loc_i,
                           const int* __restrict__ glob_b, const int* __restrict__ glob_i,
                           const float* __restrict__ gacc, float* __restrict__ psum, int n)
{
    int k = blockIdx.x * blockDim.x + threadIdx.x;
    if (k < n)
        atomicAdd(&psum[loc_b[k] * Ssz + loc_i[k]], gacc[glob_b[k] * Gsz + glob_i[k]]);
}

// K4: per-batch max, scores, mask. grid = B, block = 1024 (16 waves)
__global__ __launch_bounds__(1024) void k4_final(
    const float* __restrict__ psum, const float* __restrict__ thr_p,
    float* __restrict__ out)
{
    const int b = blockIdx.x;
    const int t = threadIdx.x;
    const float* p = psum + (size_t)b * Ssz;

    float m = -FLT_MAX;
    for (int i = t; i < Ssz; i += 1024) m = fmaxf(m, p[i]);
    #pragma unroll
    for (int off = 32; off >= 1; off >>= 1) m = fmaxf(m, __shfl_down(m, off, 64));

    __shared__ float red[16];
    const int wave = t >> 6, lane = t & 63;
    if (lane == 0) red[wave] = m;
    __syncthreads();
    if (t == 0) {
        float mm = red[0];
        #pragma unroll
        for (int w = 1; w < 16; ++w) mm = fmaxf(mm, red[w]);
        red[0] = mm;
    }
    __syncthreads();
    const float mx = red[0];
    const float thr = fmaxf(1e-5f, thr_p[0]);

    for (int i = t; i < Ssz; i += 1024) {
        float sc = p[i] / mx;
        out[(size_t)Bsz * Ssz + (size_t)b * Ssz + i] = sc;                 // scores (output 1)
        out[(size_t)b * Ssz + i] = (sc < thr) ? -10000.f : 0.f;            // mask (output 0)
    }
}

extern "C" void kernel_launch(void* const* d_in, const int* in_sizes, int n_in,
                              void* d_out, int out_size, void* d_ws, size_t ws_size,
                              hipStream_t stream)
{
    const float* mask  = (const float*)d_in[0];
    const float* probs = (const float*)d_in[1];
    const float* thr   = (const float*)d_in[2];
    // d_in[3] = max_num_global_attn_indices (hard-coded as Gsz)
    const int* loc_b  = (const int*)d_in[4];
    const int* loc_i  = (const int*)d_in[5];
    const int* glob_b = (const int*)d_in[6];
    const int* glob_i = (const int*)d_in[7];
    const int n_idx = in_sizes[4];

    float* ws     = (float*)d_ws;
    float* colsum = ws + COLSUM_OFF;
    float* psum   = ws + PSUM_OFF;
    float* gacc   = ws + GACC_OFF;
    float* out    = (float*)d_out;

    // zero psum + gacc (ws is poisoned 0xAA before every launch)
    hipMemsetAsync(psum, 0, (PSUM_SZ + GACC_SZ) * sizeof(float), stream);

    k1_rowsum<<<dim3(Bsz * Ssz / 8), dim3(256), 0, stream>>>(probs, mask, colsum, gacc);
    k2_diag<<<dim3(3, Ssz / 256, Bsz), dim3(256), 0, stream>>>(colsum, psum);
    k3_scatter<<<dim3(1), dim3(128), 0, stream>>>(loc_b, loc_i, glob_b, glob_i, gacc, psum, n_idx);
    k4_final<<<dim3(Bsz), dim3(1024), 0, stream>>>(psum, thr, out);
}

// Round 2
// 332.604 us; speedup vs baseline: 1.2165x; 1.2165x over previous
//
#include <hip/hip_runtime.h>
#include <float.h>

// Shapes (fixed by the problem)
#define Bsz 2
#define Ssz 4096
#define Hsz 12
#define Gsz 64
#define Wsz 513            // W_LOC
#define Csz (Gsz + Wsz)    // 577 channels
#define ROW (Hsz * Csz)    // 6924 floats per (b,s) row
#define HALF 256           // (Wsz-1)/2
#define RPB 8              // rows per block
#define WIN (RPB + Wsz - 1) // 520-wide output window per block

// Workspace layout (floats)
#define PSUM_SZ ((size_t)Bsz * Ssz)   // 8192
#define GACC_SZ ((size_t)Bsz * Gsz)   // 128

// K1: fused h-sum + anti-diagonal accumulation.
// Block = 256 threads, 8 consecutive rows (same b since 8 | 4096).
// Row is staged to LDS with float4; channel sums accumulate either into
// per-thread global-channel registers (c<64) or the block-local diag
// window win[(s-row0) + (c-64)] (distinct addresses per thread per row;
// the per-row __syncthreads orders cross-row aliasing).
__global__ __launch_bounds__(256) void k1_fused(
    const float* __restrict__ probs, const float* __restrict__ mask,
    float* __restrict__ psum, float* __restrict__ gacc)
{
    __shared__ float lds[ROW];     // 27,696 B
    __shared__ float win[WIN];     // 2,080 B
    const int t = threadIdx.x;
    const int row0 = blockIdx.x * RPB;
    const int b = row0 / Ssz;
    float g = 0.f;                 // thread t<64: global channel t

    for (int w = t; w < WIN; w += 256) win[w] = 0.f;
    // first __syncthreads (after staging row 0) covers this init

    for (int r = 0; r < RPB; ++r) {
        const int row = row0 + r;
        const float4* src = (const float4*)(probs + (size_t)row * ROW);
        float4* dst = (float4*)lds;
        #pragma unroll
        for (int idx = t; idx < ROW / 4; idx += 256) dst[idx] = src[idx];
        __syncthreads();

        const float scale = (mask[row] < 0.f) ? 0.f : 1.f;
        for (int c = t; c < Csz; c += 256) {
            float v = 0.f;
            #pragma unroll
            for (int h = 0; h < Hsz; ++h) v += lds[h * Csz + c];
            v *= scale;
            if (c < Gsz) g += v;
            else win[r + (c - Gsz)] += v;
        }
        __syncthreads();
    }

    // flush the 520-wide window: i = (s0 - 256) + w
    const int i_base = (row0 - b * Ssz) - HALF;
    for (int w = t; w < WIN; w += 256) {
        const int i = i_base + w;
        if (i >= 0 && i < Ssz) atomicAdd(&psum[b * Ssz + i], win[w]);
    }
    if (t < Gsz) atomicAdd(&gacc[b * Gsz + t], g);
}

// K3: honor the index arrays: psum[loc_b,loc_i] += gacc[glob_b,glob_i]
__global__ void k3_scatter(const int* __restrict__ loc_b, const int* __restrict__ loc_i,
                           const int* __restrict__ glob_b, const int* __restrict__ glob_i,
                           const float* __restrict__ gacc, float* __restrict__ psum, int n)
{
    int k = blockIdx.x * blockDim.x + threadIdx.x;
    if (k < n)
        atomicAdd(&psum[loc_b[k] * Ssz + loc_i[k]], gacc[glob_b[k] * Gsz + glob_i[k]]);
}

// K4: per-batch max, scores, mask. grid = B, block = 1024 (16 waves)
__global__ __launch_bounds__(1024) void k4_final(
    const float* __restrict__ psum, const float* __restrict__ thr_p,
    float* __restrict__ out)
{
    const int b = blockIdx.x;
    const int t = threadIdx.x;
    const float* p = psum + (size_t)b * Ssz;

    float m = -FLT_MAX;
    for (int i = t; i < Ssz; i += 1024) m = fmaxf(m, p[i]);
    #pragma unroll
    for (int off = 32; off >= 1; off >>= 1) m = fmaxf(m, __shfl_down(m, off, 64));

    __shared__ float red[16];
    const int wave = t >> 6, lane = t & 63;
    if (lane == 0) red[wave] = m;
    __syncthreads();
    if (t == 0) {
        float mm = red[0];
        #pragma unroll
        for (int w = 1; w < 16; ++w) mm = fmaxf(mm, red[w]);
        red[0] = mm;
    }
    __syncthreads();
    const float mx = red[0];
    const float thr = fmaxf(1e-5f, thr_p[0]);

    for (int i = t; i < Ssz; i += 1024) {
        float sc = p[i] / mx;
        out[(size_t)Bsz * Ssz + (size_t)b * Ssz + i] = sc;        // scores (output 1)
        out[(size_t)b * Ssz + i] = (sc < thr) ? -10000.f : 0.f;   // mask (output 0)
    }
}

extern "C" void kernel_launch(void* const* d_in, const int* in_sizes, int n_in,
                              void* d_out, int out_size, void* d_ws, size_t ws_size,
                              hipStream_t stream)
{
    const float* mask  = (const float*)d_in[0];
    const float* probs = (const float*)d_in[1];
    const float* thr   = (const float*)d_in[2];
    // d_in[3] = max_num_global_attn_indices (hard-coded as Gsz)
    const int* loc_b  = (const int*)d_in[4];
    const int* loc_i  = (const int*)d_in[5];
    const int* glob_b = (const int*)d_in[6];
    const int* glob_i = (const int*)d_in[7];
    const int n_idx = in_sizes[4];

    float* psum = (float*)d_ws;
    float* gacc = psum + PSUM_SZ;
    float* out  = (float*)d_out;

    // zero psum + gacc (ws is poisoned 0xAA before every launch)
    hipMemsetAsync(psum, 0, (PSUM_SZ + GACC_SZ) * sizeof(float), stream);

    k1_fused<<<dim3(Bsz * Ssz / RPB), dim3(256), 0, stream>>>(probs, mask, psum, gacc);
    k3_scatter<<<dim3(1), dim3(128), 0, stream>>>(loc_b, loc_i, glob_b, glob_i, gacc, psum, n_idx);
    k4_final<<<dim3(Bsz), dim3(1024), 0, stream>>>(psum, thr, out);
}